// Round 18
// baseline (372.968 us; speedup 1.0000x reference)
//
#include <hip/hip_runtime.h>
#include <hip/hip_bf16.h>
#include <math.h>

// ---------- constants ----------
// B=32, H=W=56, C=192, WS=7, SS=3, NH=6, HD=32, N=49, NW=64
#define MTOK 100352
#define SCALE_ 0.17677669529663687f

typedef short bf16x8 __attribute__((ext_vector_type(8)));
typedef float f32x4 __attribute__((ext_vector_type(4)));

__device__ __forceinline__ float b2f(unsigned short u) {
    return __uint_as_float(((unsigned int)u) << 16);
}
__device__ __forceinline__ unsigned short f2b(float f) {
    unsigned int u = __float_as_uint(f);
    unsigned int r = (u + 0x7FFFu + ((u >> 16) & 1u)) >> 16;
    return (unsigned short)r;
}
__device__ __forceinline__ void gload_lds16(const unsigned short* g, unsigned short* l) {
    __builtin_amdgcn_global_load_lds(
        (const __attribute__((address_space(1))) void*)g,
        (__attribute__((address_space(3))) void*)l, 16, 0, 0);
}

// ---------- weight convert+transpose: W[K][N] f32 -> W^T[N][K] bf16 ----------
__global__ __launch_bounds__(256) void wconv_k(
    const float* __restrict__ w, unsigned short* __restrict__ wt, int K, int N)
{
    const int i = blockIdx.x * 256 + threadIdx.x;
    if (i >= N * K) return;
    const int n = i / K, k = i - n * K;
    wt[i] = f2b(w[(size_t)k * N + n]);
}

// ---------- LN1 + cyclic shift + window partition ----------
__global__ __launch_bounds__(256) void ln1_window_k(
    const float* __restrict__ x, const float* __restrict__ g,
    const float* __restrict__ bt, unsigned short* __restrict__ out)
{
    const int wid = (blockIdx.x * 256 + threadIdx.x) >> 6;
    if (wid >= MTOK) return;
    const int lane = threadIdx.x & 63;
    const int widx = wid / 49, n = wid - widx * 49;
    const int b = widx >> 6, win = widx & 63;
    const int wh = win >> 3, ww = win & 7;
    const int r = n / 7, cc = n - r * 7;
    int hh = wh * 7 + r + 3;  if (hh >= 56) hh -= 56;
    int wc = ww * 7 + cc + 3; if (wc >= 56) wc -= 56;
    const size_t src = ((size_t)b * 3136 + hh * 56 + wc) * 192;
    const float v0 = x[src + lane], v1 = x[src + lane + 64], v2 = x[src + lane + 128];
    float s1 = v0 + v1 + v2;
    float s2 = v0 * v0 + v1 * v1 + v2 * v2;
    #pragma unroll
    for (int off = 32; off; off >>= 1) {
        s1 += __shfl_xor(s1, off, 64);
        s2 += __shfl_xor(s2, off, 64);
    }
    const float mu = s1 * (1.f / 192.f);
    const float var = s2 * (1.f / 192.f) - mu * mu;
    const float rs = rsqrtf(var + 1e-5f);
    const size_t dst = (size_t)wid * 192;
    out[dst + lane]       = f2b((v0 - mu) * rs * g[lane]       + bt[lane]);
    out[dst + lane + 64]  = f2b((v1 - mu) * rs * g[lane + 64]  + bt[lane + 64]);
    out[dst + lane + 128] = f2b((v2 - mu) * rs * g[lane + 128] + bt[lane + 128]);
}

// ---------- LN2 (token-order) ----------
__global__ __launch_bounds__(256) void ln2_k(
    const float* __restrict__ x, const float* __restrict__ g,
    const float* __restrict__ bt, unsigned short* __restrict__ out)
{
    const int t = (blockIdx.x * 256 + threadIdx.x) >> 6;
    if (t >= MTOK) return;
    const int lane = threadIdx.x & 63;
    const size_t src = (size_t)t * 192;
    const float v0 = x[src + lane], v1 = x[src + lane + 64], v2 = x[src + lane + 128];
    float s1 = v0 + v1 + v2;
    float s2 = v0 * v0 + v1 * v1 + v2 * v2;
    #pragma unroll
    for (int off = 32; off; off >>= 1) {
        s1 += __shfl_xor(s1, off, 64);
        s2 += __shfl_xor(s2, off, 64);
    }
    const float mu = s1 * (1.f / 192.f);
    const float var = s2 * (1.f / 192.f) - mu * mu;
    const float rs = rsqrtf(var + 1e-5f);
    out[src + lane]       = f2b((v0 - mu) * rs * g[lane]       + bt[lane]);
    out[src + lane + 64]  = f2b((v1 - mu) * rs * g[lane + 64]  + bt[lane + 64]);
    out[src + lane + 128] = f2b((v2 - mu) * rs * g[lane + 128] + bt[lane + 128]);
}

// ---------- MFMA GEMM: 256x64 tile + counted-vmcnt pipeline ----------
// C[M,N] = A[M,K](bf16) @ W^T[N][K](bf16). BK=32, dbuf 40 KB (~4 blocks/CU).
// 4 waves stacked in M, each wave a SQUARE 64x64 (4x4 frags): per K-step
// 8 ds_read_b128 feed 16 MFMAs (2x FLOP per barrier-crossing vs 128x64).
// Sync (R15, verified): raw s_barrier + s_waitcnt vmcnt(5) — tile t+1's 5
// global_load_lds stay in flight across the barrier; drain only at the end.
// Swizzle (verified R10): source col ((lane&3)^((lane>>3)&3))*8,
// read col (l4^((l16>>1)&3))*8 -> 0 bank conflicts.
enum { EPI_STORE_BF16 = 0, EPI_PROJ = 1, EPI_GELU = 2, EPI_RES = 3 };

template <int EPI>
__global__ __launch_bounds__(256) void mgemm_k(
    const unsigned short* __restrict__ A, const unsigned short* __restrict__ BT,
    const float* __restrict__ bias, unsigned short* __restrict__ outb,
    float* __restrict__ outf, const float* __restrict__ xres,
    int N, int K, int gx)
{
    __shared__ __align__(16) unsigned short As[2][256 * 32];  // 2x16 KB
    __shared__ __align__(16) unsigned short Bs[2][64 * 32];   // 2x 4 KB

    const int nwg = gridDim.x;
    int lin = blockIdx.x;
    lin = (lin & 7) * (nwg >> 3) + (lin >> 3);
    const int bn = lin % gx, bm = lin / gx;
    const int row0 = bm * 256, col0 = bn * 64;

    const int tid = threadIdx.x;
    const int w = tid >> 6, lane = tid & 63;
    const int l16 = lane & 15, l4 = lane >> 4;

    const unsigned short* Ab = A + (size_t)row0 * K;
    const unsigned short* Bb = BT + (size_t)col0 * K;
    const int sr = lane >> 2;
    const int sq = ((lane & 3) ^ ((lane >> 3) & 3)) * 8;

    const int nt = K >> 5;
    // prologue: stage tiles 0 and 1 (10 loads/thread in flight: 5 per tile)
    #pragma unroll
    for (int tt = 0; tt < 2; ++tt) {
        if (tt < nt) {
            const int k0 = tt << 5;
            #pragma unroll
            for (int i = 0; i < 4; i++) {
                const int ch = w * 4 + i;
                gload_lds16(Ab + (size_t)(ch * 16 + sr) * K + k0 + sq,
                            &As[tt][ch * 512 + lane * 8]);
            }
            gload_lds16(Bb + (size_t)(w * 16 + sr) * K + k0 + sq,
                        &Bs[tt][w * 512 + lane * 8]);
        }
    }

    f32x4 acc[4][4];
    #pragma unroll
    for (int m = 0; m < 4; m++)
        #pragma unroll
        for (int n = 0; n < 4; n++) acc[m][n] = (f32x4){0.f, 0.f, 0.f, 0.f};

    const int rdc = (l4 ^ ((l16 >> 1) & 3)) * 8;
    for (int t = 0; t < nt; ++t) {
        const int cur = t & 1;
        // wait for tile t only; tile t+1's 5 loads stay in flight
        if (t + 1 < nt) asm volatile("s_waitcnt vmcnt(5)" ::: "memory");
        else            asm volatile("s_waitcnt vmcnt(0)" ::: "memory");
        __builtin_amdgcn_s_barrier();
        __builtin_amdgcn_sched_barrier(0);   // keep ds_reads below the barrier
        bf16x8 af[4], bf[4];
        #pragma unroll
        for (int m = 0; m < 4; m++)
            af[m] = *reinterpret_cast<const bf16x8*>(
                &As[cur][(w * 64 + m * 16 + l16) * 32 + rdc]);
        #pragma unroll
        for (int n = 0; n < 4; n++)
            bf[n] = *reinterpret_cast<const bf16x8*>(
                &Bs[cur][(n * 16 + l16) * 32 + rdc]);
        #pragma unroll
        for (int m = 0; m < 4; m++)
            #pragma unroll
            for (int n = 0; n < 4; n++)
                acc[m][n] = __builtin_amdgcn_mfma_f32_16x16x32_bf16(
                    af[m], bf[n], acc[m][n], 0, 0, 0);
        __builtin_amdgcn_sched_barrier(0);   // all reads of buf[cur] issued above
        __builtin_amdgcn_s_barrier();        // all waves done reading buf[cur]
        if (t + 2 < nt) {
            const int k0 = (t + 2) << 5;
            #pragma unroll
            for (int i = 0; i < 4; i++) {
                const int ch = w * 4 + i;
                gload_lds16(Ab + (size_t)(ch * 16 + sr) * K + k0 + sq,
                            &As[cur][ch * 512 + lane * 8]);
            }
            gload_lds16(Bb + (size_t)(w * 16 + sr) * K + k0 + sq,
                        &Bs[cur][w * 512 + lane * 8]);
        }
    }

    // epilogue: frag (m,n) reg j -> row = row0+w*64+m*16+l4*4+j, col = col0+n*16+l16
    float bv[4];
    #pragma unroll
    for (int n = 0; n < 4; n++) bv[n] = bias[col0 + n * 16 + l16];

    #pragma unroll
    for (int m = 0; m < 4; m++) {
        #pragma unroll
        for (int j = 0; j < 4; j++) {
            const int row = row0 + w * 64 + m * 16 + l4 * 4 + j;
            if constexpr (EPI == EPI_PROJ) {
                const int widx = row / 49, n49 = row - widx * 49;
                const int b = widx >> 6, win = widx & 63;
                const int wh = win >> 3, ww = win & 7;
                const int r = n49 / 7, cc = n49 - r * 7;
                int hh = wh * 7 + r + 3;  if (hh >= 56) hh -= 56;
                int wcc = ww * 7 + cc + 3; if (wcc >= 56) wcc -= 56;
                const size_t tok = ((size_t)b * 3136 + hh * 56 + wcc) * 192;
                #pragma unroll
                for (int n = 0; n < 4; n++) {
                    const int col = col0 + n * 16 + l16;
                    outf[tok + col] = xres[tok + col] + acc[m][n][j] + bv[n];
                }
            } else if constexpr (EPI == EPI_STORE_BF16) {
                #pragma unroll
                for (int n = 0; n < 4; n++) {
                    const int col = col0 + n * 16 + l16;
                    outb[(size_t)row * N + col] = f2b(acc[m][n][j] + bv[n]);
                }
            } else if constexpr (EPI == EPI_GELU) {
                #pragma unroll
                for (int n = 0; n < 4; n++) {
                    const int col = col0 + n * 16 + l16;
                    float v = acc[m][n][j] + bv[n];
                    const float wv = v + 0.044715f * v * v * v;
                    const float sg = __builtin_amdgcn_rcpf(
                        1.f + __expf(-1.5957691216057308f * wv));
                    v = v * sg;
                    outb[(size_t)row * N + col] = f2b(v);
                }
            } else {  // EPI_RES
                #pragma unroll
                for (int n = 0; n < 4; n++) {
                    const int col = col0 + n * 16 + l16;
                    outf[(size_t)row * N + col] += acc[m][n][j] + bv[n];
                }
            }
        }
    }
}

// ---------- MFMA attention: one wave (64 thr) per (window, head) ----------
__global__ __launch_bounds__(64) void attn_mfma_k(
    const unsigned short* __restrict__ qkv, const float* __restrict__ rpb,
    unsigned short* __restrict__ out)
{
    const int blk = blockIdx.x;
    const int widx = blk / 6, head = blk - widx * 6;
    const int win = widx & 63;
    const int wh = win >> 3, ww = win & 7;

    __shared__ __align__(16) unsigned short vt[32 * 72];  // V^T [d][m], stride 72
    __shared__ __align__(16) unsigned short pl[64 * 72];  // P  [n][m], stride 72
    __shared__ float bias_s[256];

    const int lane = threadIdx.x;
    const int l16 = lane & 15, l4 = lane >> 4;
    const size_t base = (size_t)widx * 49 * 576 + (size_t)head * 32;

    for (int i = lane; i < 169; i += 64) bias_s[i] = rpb[i * 6 + head];

    #pragma unroll
    for (int it = 0; it < 4; ++it) {
        const int c = lane + it * 64;
        const int m = c >> 2, d8 = (c & 3) * 8;
        bf16x8 v8 = {};
        if (m < 49)
            v8 = *reinterpret_cast<const bf16x8*>(qkv + base + (size_t)m * 576 + 384 + d8);
        #pragma unroll
        for (int r = 0; r < 8; ++r) vt[(d8 + r) * 72 + m] = (unsigned short)v8[r];
    }

    bf16x8 kf[4], qf[4];
    #pragma unroll
    for (int f = 0; f < 4; ++f) {
        const int rrow = f * 16 + l16;
        bf16x8 kz = {}, qz = {};
        if (rrow < 49) {
            kz = *reinterpret_cast<const bf16x8*>(qkv + base + (size_t)rrow * 576 + 192 + l4 * 8);
            qz = *reinterpret_cast<const bf16x8*>(qkv + base + (size_t)rrow * 576 + l4 * 8);
        }
        kf[f] = kz; qf[f] = qz;
    }

    f32x4 acc[4][4];
    __builtin_amdgcn_s_setprio(1);
    #pragma unroll
    for (int mf = 0; mf < 4; ++mf)
        #pragma unroll
        for (int nf = 0; nf < 4; ++nf) {
            f32x4 z = (f32x4){0.f, 0.f, 0.f, 0.f};
            acc[mf][nf] = __builtin_amdgcn_mfma_f32_16x16x32_bf16(kf[mf], qf[nf], z, 0, 0, 0);
        }
    __builtin_amdgcn_s_setprio(0);

    __syncthreads();

    int gn[4], labn[4]; bool nok[4];
    #pragma unroll
    for (int nf = 0; nf < 4; ++nf) {
        const int n = nf * 16 + l16;
        const int rn = (n * 9363) >> 16, cn = n - rn * 7;
        gn[nf] = n + 6 * rn;
        labn[nf] = (wh == 7 ? (rn < 4 ? 1 : 2) : 0) * 3 + (ww == 7 ? (cn < 4 ? 1 : 2) : 0);
        nok[nf] = (n < 49);
    }

    #pragma unroll
    for (int mf = 0; mf < 4; ++mf) {
        #pragma unroll
        for (int j = 0; j < 4; ++j) {
            const int m = mf * 16 + l4 * 4 + j;
            const int rm = (m * 9363) >> 16, cm = m - rm * 7;
            const int gm = m + 6 * rm;
            const int labm = (wh == 7 ? (rm < 4 ? 1 : 2) : 0) * 3 + (ww == 7 ? (cm < 4 ? 1 : 2) : 0);
            const bool mok = (m < 49);
            #pragma unroll
            for (int nf = 0; nf < 4; ++nf) {
                float s = -1e30f;
                if (mok && nok[nf]) {
                    s = acc[mf][nf][j] * SCALE_ + bias_s[gn[nf] - gm + 84];
                    if (labn[nf] != labm) s -= 100.f;
                }
                acc[mf][nf][j] = s;
            }
        }
    }

    #pragma unroll
    for (int nf = 0; nf < 4; ++nf) {
        float mx = -1e30f;
        #pragma unroll
        for (int mf = 0; mf < 4; ++mf)
            #pragma unroll
            for (int j = 0; j < 4; ++j) mx = fmaxf(mx, acc[mf][nf][j]);
        mx = fmaxf(mx, __shfl_xor(mx, 16, 64));
        mx = fmaxf(mx, __shfl_xor(mx, 32, 64));
        float sum = 0.f;
        #pragma unroll
        for (int mf = 0; mf < 4; ++mf)
            #pragma unroll
            for (int j = 0; j < 4; ++j) {
                const float e = __expf(acc[mf][nf][j] - mx);
                acc[mf][nf][j] = e;
                sum += e;
            }
        sum += __shfl_xor(sum, 16, 64);
        sum += __shfl_xor(sum, 32, 64);
        const float inv = 1.f / sum;
        const int n = nf * 16 + l16;
        #pragma unroll
        for (int mf = 0; mf < 4; ++mf)
            #pragma unroll
            for (int jp = 0; jp < 2; ++jp) {
                const int m = mf * 16 + l4 * 4 + jp * 2;
                const unsigned int pk =
                    (unsigned int)f2b(acc[mf][nf][jp * 2] * inv) |
                    ((unsigned int)f2b(acc[mf][nf][jp * 2 + 1] * inv) << 16);
                *reinterpret_cast<unsigned int*>(&pl[n * 72 + m]) = pk;
            }
    }
    __syncthreads();

    f32x4 oacc[4][2];
    #pragma unroll
    for (int nf = 0; nf < 4; ++nf)
        #pragma unroll
        for (int df = 0; df < 2; ++df) oacc[nf][df] = (f32x4){0.f, 0.f, 0.f, 0.f};
    #pragma unroll
    for (int ks = 0; ks < 2; ++ks) {
        bf16x8 vf[2];
        #pragma unroll
        for (int df = 0; df < 2; ++df)
            vf[df] = *reinterpret_cast<const bf16x8*>(&vt[(df * 16 + l16) * 72 + ks * 32 + l4 * 8]);
        __builtin_amdgcn_s_setprio(1);
        #pragma unroll
        for (int nf = 0; nf < 4; ++nf) {
            const bf16x8 pf = *reinterpret_cast<const bf16x8*>(&pl[(nf * 16 + l16) * 72 + ks * 32 + l4 * 8]);
            #pragma unroll
            for (int df = 0; df < 2; ++df)
                oacc[nf][df] = __builtin_amdgcn_mfma_f32_16x16x32_bf16(pf, vf[df], oacc[nf][df], 0, 0, 0);
        }
        __builtin_amdgcn_s_setprio(0);
    }

    #pragma unroll
    for (int nf = 0; nf < 4; ++nf)
        #pragma unroll
        for (int j = 0; j < 4; ++j) {
            const int n = nf * 16 + l4 * 4 + j;
            if (n < 49) {
                const size_t o = ((size_t)widx * 49 + n) * 192 + (size_t)head * 32;
                out[o + l16]      = f2b(oacc[nf][0][j]);
                out[o + 16 + l16] = f2b(oacc[nf][1][j]);
            }
        }
}

// ---------- launch ----------
extern "C" void kernel_launch(void* const* d_in, const int* in_sizes, int n_in,
                              void* d_out, int out_size, void* d_ws, size_t ws_size,
                              hipStream_t stream)
{
    const float* x      = (const float*)d_in[0];
    const float* n1g    = (const float*)d_in[1];
    const float* n1b    = (const float*)d_in[2];
    const float* qkv_w  = (const float*)d_in[3];
    const float* qkv_b  = (const float*)d_in[4];
    const float* rpb    = (const float*)d_in[5];
    const float* proj_w = (const float*)d_in[6];
    const float* proj_b = (const float*)d_in[7];
    const float* n2g    = (const float*)d_in[8];
    const float* n2b    = (const float*)d_in[9];
    const float* fc1_w  = (const float*)d_in[10];
    const float* fc1_b  = (const float*)d_in[11];
    const float* fc2_w  = (const float*)d_in[12];
    const float* fc2_b  = (const float*)d_in[13];
    float* out = (float*)d_out;

    const int M = MTOK;  // 100352 = 392*256
    unsigned short* big   = (unsigned short*)d_ws;          // M*768
    unsigned short* winx  = big + (size_t)M * 768;          // M*192 (ln1-win, attn-out, ln2-out)
    unsigned short* qkvT  = winx + (size_t)M * 192;         // 576*192
    unsigned short* projT = qkvT + 576 * 192;               // 192*192
    unsigned short* fc1T  = projT + 192 * 192;              // 768*192
    unsigned short* fc2T  = fc1T + 768 * 192;               // 192*768

    // 0) weights -> bf16 transposed
    wconv_k<<<(576 * 192 + 255) / 256, 256, 0, stream>>>(qkv_w, qkvT, 192, 576);
    wconv_k<<<(192 * 192 + 255) / 256, 256, 0, stream>>>(proj_w, projT, 192, 192);
    wconv_k<<<(768 * 192 + 255) / 256, 256, 0, stream>>>(fc1_w, fc1T, 192, 768);
    wconv_k<<<(192 * 768 + 255) / 256, 256, 0, stream>>>(fc2_w, fc2T, 768, 192);

    // 1) LN1 + shift + window partition -> winx (bf16)
    ln1_window_k<<<M / 4, 256, 0, stream>>>(x, n1g, n1b, winx);
    // 2) qkv: (M,192)@(192,576) -> big
    mgemm_k<EPI_STORE_BF16><<<9 * (M / 256), 256, 0, stream>>>(
        winx, qkvT, qkv_b, big, nullptr, nullptr, 576, 192, 9);
    // 3) attention (MFMA, one wave per window×head) -> winx
    attn_mfma_k<<<2048 * 6, 64, 0, stream>>>(big, rpb, winx);
    // 4) proj + window-reverse + unshift + residual -> d_out (f32)
    mgemm_k<EPI_PROJ><<<3 * (M / 256), 256, 0, stream>>>(
        winx, projT, proj_b, nullptr, out, x, 192, 192, 3);
    // 5) LN2 -> winx (bf16)
    ln2_k<<<M / 4, 256, 0, stream>>>(out, n2g, n2b, winx);
    // 6) fc1 + GELU -> big
    mgemm_k<EPI_GELU><<<12 * (M / 256), 256, 0, stream>>>(
        winx, fc1T, fc1_b, big, nullptr, nullptr, 768, 192, 12);
    // 7) fc2 + residual -> d_out
    mgemm_k<EPI_RES><<<3 * (M / 256), 256, 0, stream>>>(
        big, fc2T, fc2_b, nullptr, out, nullptr, 192, 768, 3);
}

// Round 22
// 370.598 us; speedup vs baseline: 1.0064x; 1.0064x over previous
//
#include <hip/hip_runtime.h>
#include <hip/hip_bf16.h>
#include <math.h>

// ---------- constants ----------
// B=32, H=W=56, C=192, WS=7, SS=3, NH=6, HD=32, N=49, NW=64
#define MTOK 100352
#define SCALE_ 0.17677669529663687f

typedef short bf16x8 __attribute__((ext_vector_type(8)));
typedef float f32x4 __attribute__((ext_vector_type(4)));

__device__ __forceinline__ float b2f(unsigned short u) {
    return __uint_as_float(((unsigned int)u) << 16);
}
__device__ __forceinline__ unsigned short f2b(float f) {
    unsigned int u = __float_as_uint(f);
    unsigned int r = (u + 0x7FFFu + ((u >> 16) & 1u)) >> 16;
    return (unsigned short)r;
}
__device__ __forceinline__ void gload_lds16(const unsigned short* g, unsigned short* l) {
    __builtin_amdgcn_global_load_lds(
        (const __attribute__((address_space(1))) void*)g,
        (__attribute__((address_space(3))) void*)l, 16, 0, 0);
}

// ---------- weight convert+transpose: W[K][N] f32 -> W^T[N][K] bf16 ----------
__global__ __launch_bounds__(256) void wconv_k(
    const float* __restrict__ w, unsigned short* __restrict__ wt, int K, int N)
{
    const int i = blockIdx.x * 256 + threadIdx.x;
    if (i >= N * K) return;
    const int n = i / K, k = i - n * K;
    wt[i] = f2b(w[(size_t)k * N + n]);
}

// ---------- LN1 + cyclic shift + window partition ----------
__global__ __launch_bounds__(256) void ln1_window_k(
    const float* __restrict__ x, const float* __restrict__ g,
    const float* __restrict__ bt, unsigned short* __restrict__ out)
{
    const int wid = (blockIdx.x * 256 + threadIdx.x) >> 6;
    if (wid >= MTOK) return;
    const int lane = threadIdx.x & 63;
    const int widx = wid / 49, n = wid - widx * 49;
    const int b = widx >> 6, win = widx & 63;
    const int wh = win >> 3, ww = win & 7;
    const int r = n / 7, cc = n - r * 7;
    int hh = wh * 7 + r + 3;  if (hh >= 56) hh -= 56;
    int wc = ww * 7 + cc + 3; if (wc >= 56) wc -= 56;
    const size_t src = ((size_t)b * 3136 + hh * 56 + wc) * 192;
    const float v0 = x[src + lane], v1 = x[src + lane + 64], v2 = x[src + lane + 128];
    float s1 = v0 + v1 + v2;
    float s2 = v0 * v0 + v1 * v1 + v2 * v2;
    #pragma unroll
    for (int off = 32; off; off >>= 1) {
        s1 += __shfl_xor(s1, off, 64);
        s2 += __shfl_xor(s2, off, 64);
    }
    const float mu = s1 * (1.f / 192.f);
    const float var = s2 * (1.f / 192.f) - mu * mu;
    const float rs = rsqrtf(var + 1e-5f);
    const size_t dst = (size_t)wid * 192;
    out[dst + lane]       = f2b((v0 - mu) * rs * g[lane]       + bt[lane]);
    out[dst + lane + 64]  = f2b((v1 - mu) * rs * g[lane + 64]  + bt[lane + 64]);
    out[dst + lane + 128] = f2b((v2 - mu) * rs * g[lane + 128] + bt[lane + 128]);
}

// ---------- LN2 (token-order) ----------
__global__ __launch_bounds__(256) void ln2_k(
    const float* __restrict__ x, const float* __restrict__ g,
    const float* __restrict__ bt, unsigned short* __restrict__ out)
{
    const int t = (blockIdx.x * 256 + threadIdx.x) >> 6;
    if (t >= MTOK) return;
    const int lane = threadIdx.x & 63;
    const size_t src = (size_t)t * 192;
    const float v0 = x[src + lane], v1 = x[src + lane + 64], v2 = x[src + lane + 128];
    float s1 = v0 + v1 + v2;
    float s2 = v0 * v0 + v1 * v1 + v2 * v2;
    #pragma unroll
    for (int off = 32; off; off >>= 1) {
        s1 += __shfl_xor(s1, off, 64);
        s2 += __shfl_xor(s2, off, 64);
    }
    const float mu = s1 * (1.f / 192.f);
    const float var = s2 * (1.f / 192.f) - mu * mu;
    const float rs = rsqrtf(var + 1e-5f);
    out[src + lane]       = f2b((v0 - mu) * rs * g[lane]       + bt[lane]);
    out[src + lane + 64]  = f2b((v1 - mu) * rs * g[lane + 64]  + bt[lane + 64]);
    out[src + lane + 128] = f2b((v2 - mu) * rs * g[lane + 128] + bt[lane + 128]);
}

// ---------- MFMA GEMM (R15 structure + counted-vmcnt pipeline) ----------
// C[M,N] = A[M,K](bf16) @ W^T[N][K](bf16). tile 128x64, BK=32, dbuf 24 KB.
// K-loop sync: raw s_barrier + s_waitcnt vmcnt(3) — tile t+1's 3 global_load_lds
// stay IN FLIGHT across the barrier (never drain to 0 until the last step).
// Swizzle (verified R10, 0 conflicts): source col ((lane&3)^((lane>>3)&3))*8,
// read col (l4^((l16>>1)&3))*8.
enum { EPI_STORE_BF16 = 0, EPI_PROJ = 1, EPI_GELU = 2, EPI_RES = 3 };

template <int EPI>
__global__ __launch_bounds__(256) void mgemm_k(
    const unsigned short* __restrict__ A, const unsigned short* __restrict__ BT,
    const float* __restrict__ bias, unsigned short* __restrict__ outb,
    float* __restrict__ outf, const float* __restrict__ xres,
    int N, int K, int gx)
{
    __shared__ __align__(16) unsigned short As[2][128 * 32];  // 2x8 KB
    __shared__ __align__(16) unsigned short Bs[2][64 * 32];   // 2x4 KB

    const int nwg = gridDim.x;
    int lin = blockIdx.x;
    lin = (lin & 7) * (nwg >> 3) + (lin >> 3);
    const int bn = lin % gx, bm = lin / gx;
    const int row0 = bm * 128, col0 = bn * 64;

    const int tid = threadIdx.x;
    const int w = tid >> 6, lane = tid & 63;
    const int wr = w >> 1, wc = w & 1;
    const int l16 = lane & 15, l4 = lane >> 4;

    const unsigned short* Ab = A + (size_t)row0 * K;
    const unsigned short* Bb = BT + (size_t)col0 * K;
    const int sr = lane >> 2;
    const int sq = ((lane & 3) ^ ((lane >> 3) & 3)) * 8;

    // prologue: stage tiles 0 and 1 (6 loads/thread in flight)
    #pragma unroll
    for (int i = 0; i < 2; i++) {
        const int ch = w * 2 + i;
        gload_lds16(Ab + (size_t)(ch * 16 + sr) * K + sq, &As[0][ch * 512 + lane * 8]);
    }
    gload_lds16(Bb + (size_t)(w * 16 + sr) * K + sq, &Bs[0][w * 512 + lane * 8]);
    const int nt = K >> 5;
    if (nt > 1) {
        #pragma unroll
        for (int i = 0; i < 2; i++) {
            const int ch = w * 2 + i;
            gload_lds16(Ab + (size_t)(ch * 16 + sr) * K + 32 + sq, &As[1][ch * 512 + lane * 8]);
        }
        gload_lds16(Bb + (size_t)(w * 16 + sr) * K + 32 + sq, &Bs[1][w * 512 + lane * 8]);
    }

    f32x4 acc[4][2];
    #pragma unroll
    for (int m = 0; m < 4; m++)
        #pragma unroll
        for (int n = 0; n < 2; n++) acc[m][n] = (f32x4){0.f, 0.f, 0.f, 0.f};

    const int rdc = (l4 ^ ((l16 >> 1) & 3)) * 8;
    for (int t = 0; t < nt; ++t) {
        const int cur = t & 1;
        // wait for tile t only; tile t+1's 3 loads stay in flight
        if (t + 1 < nt) asm volatile("s_waitcnt vmcnt(3)" ::: "memory");
        else            asm volatile("s_waitcnt vmcnt(0)" ::: "memory");
        __builtin_amdgcn_s_barrier();
        __builtin_amdgcn_sched_barrier(0);   // keep ds_reads below the barrier
        bf16x8 af[4], bf[2];
        #pragma unroll
        for (int m = 0; m < 4; m++)
            af[m] = *reinterpret_cast<const bf16x8*>(
                &As[cur][(wr * 64 + m * 16 + l16) * 32 + rdc]);
        #pragma unroll
        for (int n = 0; n < 2; n++)
            bf[n] = *reinterpret_cast<const bf16x8*>(
                &Bs[cur][(wc * 32 + n * 16 + l16) * 32 + rdc]);
        #pragma unroll
        for (int m = 0; m < 4; m++)
            #pragma unroll
            for (int n = 0; n < 2; n++)
                acc[m][n] = __builtin_amdgcn_mfma_f32_16x16x32_bf16(
                    af[m], bf[n], acc[m][n], 0, 0, 0);
        __builtin_amdgcn_sched_barrier(0);   // all reads of buf[cur] issued above
        __builtin_amdgcn_s_barrier();        // all waves done reading buf[cur]
        if (t + 2 < nt) {
            const int k0 = (t + 2) << 5;
            #pragma unroll
            for (int i = 0; i < 2; i++) {
                const int ch = w * 2 + i;
                gload_lds16(Ab + (size_t)(ch * 16 + sr) * K + k0 + sq,
                            &As[cur][ch * 512 + lane * 8]);
            }
            gload_lds16(Bb + (size_t)(w * 16 + sr) * K + k0 + sq,
                        &Bs[cur][w * 512 + lane * 8]);
        }
    }

    float bv[2];
    #pragma unroll
    for (int n = 0; n < 2; n++) bv[n] = bias[col0 + wc * 32 + n * 16 + l16];

    #pragma unroll
    for (int m = 0; m < 4; m++) {
        #pragma unroll
        for (int j = 0; j < 4; j++) {
            const int row = row0 + wr * 64 + m * 16 + l4 * 4 + j;
            if constexpr (EPI == EPI_PROJ) {
                const int widx = row / 49, n49 = row - widx * 49;
                const int b = widx >> 6, win = widx & 63;
                const int wh = win >> 3, ww = win & 7;
                const int r = n49 / 7, cc = n49 - r * 7;
                int hh = wh * 7 + r + 3;  if (hh >= 56) hh -= 56;
                int wcc = ww * 7 + cc + 3; if (wcc >= 56) wcc -= 56;
                const size_t tok = ((size_t)b * 3136 + hh * 56 + wcc) * 192;
                #pragma unroll
                for (int n = 0; n < 2; n++) {
                    const int col = col0 + wc * 32 + n * 16 + l16;
                    outf[tok + col] = xres[tok + col] + acc[m][n][j] + bv[n];
                }
            } else if constexpr (EPI == EPI_STORE_BF16) {
                #pragma unroll
                for (int n = 0; n < 2; n++) {
                    const int col = col0 + wc * 32 + n * 16 + l16;
                    outb[(size_t)row * N + col] = f2b(acc[m][n][j] + bv[n]);
                }
            } else if constexpr (EPI == EPI_GELU) {
                #pragma unroll
                for (int n = 0; n < 2; n++) {
                    const int col = col0 + wc * 32 + n * 16 + l16;
                    float v = acc[m][n][j] + bv[n];
                    const float wv = v + 0.044715f * v * v * v;
                    const float sg = __builtin_amdgcn_rcpf(
                        1.f + __expf(-1.5957691216057308f * wv));
                    v = v * sg;
                    outb[(size_t)row * N + col] = f2b(v);
                }
            } else {  // EPI_RES
                #pragma unroll
                for (int n = 0; n < 2; n++) {
                    const int col = col0 + wc * 32 + n * 16 + l16;
                    outf[(size_t)row * N + col] += acc[m][n][j] + bv[n];
                }
            }
        }
    }
}

// ---------- MFMA attention: one wave (64 thr) per (window, head) ----------
__global__ __launch_bounds__(64) void attn_mfma_k(
    const unsigned short* __restrict__ qkv, const float* __restrict__ rpb,
    unsigned short* __restrict__ out)
{
    const int blk = blockIdx.x;
    const int widx = blk / 6, head = blk - widx * 6;
    const int win = widx & 63;
    const int wh = win >> 3, ww = win & 7;

    __shared__ __align__(16) unsigned short vt[32 * 72];  // V^T [d][m], stride 72
    __shared__ __align__(16) unsigned short pl[64 * 72];  // P  [n][m], stride 72
    __shared__ float bias_s[256];

    const int lane = threadIdx.x;
    const int l16 = lane & 15, l4 = lane >> 4;
    const size_t base = (size_t)widx * 49 * 576 + (size_t)head * 32;

    for (int i = lane; i < 169; i += 64) bias_s[i] = rpb[i * 6 + head];

    #pragma unroll
    for (int it = 0; it < 4; ++it) {
        const int c = lane + it * 64;
        const int m = c >> 2, d8 = (c & 3) * 8;
        bf16x8 v8 = {};
        if (m < 49)
            v8 = *reinterpret_cast<const bf16x8*>(qkv + base + (size_t)m * 576 + 384 + d8);
        #pragma unroll
        for (int r = 0; r < 8; ++r) vt[(d8 + r) * 72 + m] = (unsigned short)v8[r];
    }

    bf16x8 kf[4], qf[4];
    #pragma unroll
    for (int f = 0; f < 4; ++f) {
        const int rrow = f * 16 + l16;
        bf16x8 kz = {}, qz = {};
        if (rrow < 49) {
            kz = *reinterpret_cast<const bf16x8*>(qkv + base + (size_t)rrow * 576 + 192 + l4 * 8);
            qz = *reinterpret_cast<const bf16x8*>(qkv + base + (size_t)rrow * 576 + l4 * 8);
        }
        kf[f] = kz; qf[f] = qz;
    }

    f32x4 acc[4][4];
    #pragma unroll
    for (int mf = 0; mf < 4; ++mf)
        #pragma unroll
        for (int nf = 0; nf < 4; ++nf) {
            f32x4 z = (f32x4){0.f, 0.f, 0.f, 0.f};
            acc[mf][nf] = __builtin_amdgcn_mfma_f32_16x16x32_bf16(kf[mf], qf[nf], z, 0, 0, 0);
        }

    __syncthreads();

    int gn[4], labn[4]; bool nok[4];
    #pragma unroll
    for (int nf = 0; nf < 4; ++nf) {
        const int n = nf * 16 + l16;
        const int rn = (n * 9363) >> 16, cn = n - rn * 7;
        gn[nf] = n + 6 * rn;
        labn[nf] = (wh == 7 ? (rn < 4 ? 1 : 2) : 0) * 3 + (ww == 7 ? (cn < 4 ? 1 : 2) : 0);
        nok[nf] = (n < 49);
    }

    #pragma unroll
    for (int mf = 0; mf < 4; ++mf) {
        #pragma unroll
        for (int j = 0; j < 4; ++j) {
            const int m = mf * 16 + l4 * 4 + j;
            const int rm = (m * 9363) >> 16, cm = m - rm * 7;
            const int gm = m + 6 * rm;
            const int labm = (wh == 7 ? (rm < 4 ? 1 : 2) : 0) * 3 + (ww == 7 ? (cm < 4 ? 1 : 2) : 0);
            const bool mok = (m < 49);
            #pragma unroll
            for (int nf = 0; nf < 4; ++nf) {
                float s = -1e30f;
                if (mok && nok[nf]) {
                    s = acc[mf][nf][j] * SCALE_ + bias_s[gn[nf] - gm + 84];
                    if (labn[nf] != labm) s -= 100.f;
                }
                acc[mf][nf][j] = s;
            }
        }
    }

    #pragma unroll
    for (int nf = 0; nf < 4; ++nf) {
        float mx = -1e30f;
        #pragma unroll
        for (int mf = 0; mf < 4; ++mf)
            #pragma unroll
            for (int j = 0; j < 4; ++j) mx = fmaxf(mx, acc[mf][nf][j]);
        mx = fmaxf(mx, __shfl_xor(mx, 16, 64));
        mx = fmaxf(mx, __shfl_xor(mx, 32, 64));
        float sum = 0.f;
        #pragma unroll
        for (int mf = 0; mf < 4; ++mf)
            #pragma unroll
            for (int j = 0; j < 4; ++j) {
                const float e = __expf(acc[mf][nf][j] - mx);
                acc[mf][nf][j] = e;
                sum += e;
            }
        sum += __shfl_xor(sum, 16, 64);
        sum += __shfl_xor(sum, 32, 64);
        const float inv = 1.f / sum;
        const int n = nf * 16 + l16;
        #pragma unroll
        for (int mf = 0; mf < 4; ++mf)
            #pragma unroll
            for (int jp = 0; jp < 2; ++jp) {
                const int m = mf * 16 + l4 * 4 + jp * 2;
                const unsigned int pk =
                    (unsigned int)f2b(acc[mf][nf][jp * 2] * inv) |
                    ((unsigned int)f2b(acc[mf][nf][jp * 2 + 1] * inv) << 16);
                *reinterpret_cast<unsigned int*>(&pl[n * 72 + m]) = pk;
            }
    }
    __syncthreads();

    f32x4 oacc[4][2];
    #pragma unroll
    for (int nf = 0; nf < 4; ++nf)
        #pragma unroll
        for (int df = 0; df < 2; ++df) oacc[nf][df] = (f32x4){0.f, 0.f, 0.f, 0.f};
    #pragma unroll
    for (int ks = 0; ks < 2; ++ks) {
        bf16x8 vf[2];
        #pragma unroll
        for (int df = 0; df < 2; ++df)
            vf[df] = *reinterpret_cast<const bf16x8*>(&vt[(df * 16 + l16) * 72 + ks * 32 + l4 * 8]);
        #pragma unroll
        for (int nf = 0; nf < 4; ++nf) {
            const bf16x8 pf = *reinterpret_cast<const bf16x8*>(&pl[(nf * 16 + l16) * 72 + ks * 32 + l4 * 8]);
            #pragma unroll
            for (int df = 0; df < 2; ++df)
                oacc[nf][df] = __builtin_amdgcn_mfma_f32_16x16x32_bf16(pf, vf[df], oacc[nf][df], 0, 0, 0);
        }
    }

    #pragma unroll
    for (int nf = 0; nf < 4; ++nf)
        #pragma unroll
        for (int j = 0; j < 4; ++j) {
            const int n = nf * 16 + l4 * 4 + j;
            if (n < 49) {
                const size_t o = ((size_t)widx * 49 + n) * 192 + (size_t)head * 32;
                out[o + l16]      = f2b(oacc[nf][0][j]);
                out[o + 16 + l16] = f2b(oacc[nf][1][j]);
            }
        }
}

// ---------- launch ----------
extern "C" void kernel_launch(void* const* d_in, const int* in_sizes, int n_in,
                              void* d_out, int out_size, void* d_ws, size_t ws_size,
                              hipStream_t stream)
{
    const float* x      = (const float*)d_in[0];
    const float* n1g    = (const float*)d_in[1];
    const float* n1b    = (const float*)d_in[2];
    const float* qkv_w  = (const float*)d_in[3];
    const float* qkv_b  = (const float*)d_in[4];
    const float* rpb    = (const float*)d_in[5];
    const float* proj_w = (const float*)d_in[6];
    const float* proj_b = (const float*)d_in[7];
    const float* n2g    = (const float*)d_in[8];
    const float* n2b    = (const float*)d_in[9];
    const float* fc1_w  = (const float*)d_in[10];
    const float* fc1_b  = (const float*)d_in[11];
    const float* fc2_w  = (const float*)d_in[12];
    const float* fc2_b  = (const float*)d_in[13];
    float* out = (float*)d_out;

    const int M = MTOK;  // 100352 = 784*128
    unsigned short* big   = (unsigned short*)d_ws;          // M*768
    unsigned short* winx  = big + (size_t)M * 768;          // M*192 (ln1-win, attn-out, ln2-out)
    unsigned short* qkvT  = winx + (size_t)M * 192;         // 576*192
    unsigned short* projT = qkvT + 576 * 192;               // 192*192
    unsigned short* fc1T  = projT + 192 * 192;              // 768*192
    unsigned short* fc2T  = fc1T + 768 * 192;               // 192*768

    // 0) weights -> bf16 transposed
    wconv_k<<<(576 * 192 + 255) / 256, 256, 0, stream>>>(qkv_w, qkvT, 192, 576);
    wconv_k<<<(192 * 192 + 255) / 256, 256, 0, stream>>>(proj_w, projT, 192, 192);
    wconv_k<<<(768 * 192 + 255) / 256, 256, 0, stream>>>(fc1_w, fc1T, 192, 768);
    wconv_k<<<(192 * 768 + 255) / 256, 256, 0, stream>>>(fc2_w, fc2T, 768, 192);

    // 1) LN1 + shift + window partition -> winx (bf16)
    ln1_window_k<<<M / 4, 256, 0, stream>>>(x, n1g, n1b, winx);
    // 2) qkv: (M,192)@(192,576) -> big
    mgemm_k<EPI_STORE_BF16><<<9 * (M / 128), 256, 0, stream>>>(
        winx, qkvT, qkv_b, big, nullptr, nullptr, 576, 192, 9);
    // 3) attention (MFMA, one wave per window×head) -> winx
    attn_mfma_k<<<2048 * 6, 64, 0, stream>>>(big, rpb, winx);
    // 4) proj + window-reverse + unshift + residual -> d_out (f32)
    mgemm_k<EPI_PROJ><<<3 * (M / 128), 256, 0, stream>>>(
        winx, projT, proj_b, nullptr, out, x, 192, 192, 3);
    // 5) LN2 -> winx (bf16)
    ln2_k<<<M / 4, 256, 0, stream>>>(out, n2g, n2b, winx);
    // 6) fc1 + GELU -> big
    mgemm_k<EPI_GELU><<<12 * (M / 128), 256, 0, stream>>>(
        winx, fc1T, fc1_b, big, nullptr, nullptr, 768, 192, 12);
    // 7) fc2 + residual -> d_out
    mgemm_k<EPI_RES><<<3 * (M / 128), 256, 0, stream>>>(
        big, fc2T, fc2_b, nullptr, out, nullptr, 192, 768, 3);
}

// Round 23
// 369.487 us; speedup vs baseline: 1.0094x; 1.0030x over previous
//
#include <hip/hip_runtime.h>
#include <hip/hip_bf16.h>
#include <math.h>

// ---------- constants ----------
// B=32, H=W=56, C=192, WS=7, SS=3, NH=6, HD=32, N=49, NW=64
#define MTOK 100352
#define SCALE_ 0.17677669529663687f

typedef short bf16x8 __attribute__((ext_vector_type(8)));
typedef float f32x4 __attribute__((ext_vector_type(4)));

__device__ __forceinline__ float b2f(unsigned short u) {
    return __uint_as_float(((unsigned int)u) << 16);
}
__device__ __forceinline__ unsigned short f2b(float f) {
    unsigned int u = __float_as_uint(f);
    unsigned int r = (u + 0x7FFFu + ((u >> 16) & 1u)) >> 16;
    return (unsigned short)r;
}
__device__ __forceinline__ void gload_lds16(const unsigned short* g, unsigned short* l) {
    __builtin_amdgcn_global_load_lds(
        (const __attribute__((address_space(1))) void*)g,
        (__attribute__((address_space(3))) void*)l, 16, 0, 0);
}

// ---------- weight convert+transpose: W[K][N] f32 -> W^T[N][K] bf16 ----------
__global__ __launch_bounds__(256) void wconv_k(
    const float* __restrict__ w, unsigned short* __restrict__ wt, int K, int N)
{
    const int i = blockIdx.x * 256 + threadIdx.x;
    if (i >= N * K) return;
    const int n = i / K, k = i - n * K;
    wt[i] = f2b(w[(size_t)k * N + n]);
}

// ---------- LN1 + cyclic shift + window partition ----------
__global__ __launch_bounds__(256) void ln1_window_k(
    const float* __restrict__ x, const float* __restrict__ g,
    const float* __restrict__ bt, unsigned short* __restrict__ out)
{
    const int wid = (blockIdx.x * 256 + threadIdx.x) >> 6;
    if (wid >= MTOK) return;
    const int lane = threadIdx.x & 63;
    const int widx = wid / 49, n = wid - widx * 49;
    const int b = widx >> 6, win = widx & 63;
    const int wh = win >> 3, ww = win & 7;
    const int r = n / 7, cc = n - r * 7;
    int hh = wh * 7 + r + 3;  if (hh >= 56) hh -= 56;
    int wc = ww * 7 + cc + 3; if (wc >= 56) wc -= 56;
    const size_t src = ((size_t)b * 3136 + hh * 56 + wc) * 192;
    const float v0 = x[src + lane], v1 = x[src + lane + 64], v2 = x[src + lane + 128];
    float s1 = v0 + v1 + v2;
    float s2 = v0 * v0 + v1 * v1 + v2 * v2;
    #pragma unroll
    for (int off = 32; off; off >>= 1) {
        s1 += __shfl_xor(s1, off, 64);
        s2 += __shfl_xor(s2, off, 64);
    }
    const float mu = s1 * (1.f / 192.f);
    const float var = s2 * (1.f / 192.f) - mu * mu;
    const float rs = rsqrtf(var + 1e-5f);
    const size_t dst = (size_t)wid * 192;
    out[dst + lane]       = f2b((v0 - mu) * rs * g[lane]       + bt[lane]);
    out[dst + lane + 64]  = f2b((v1 - mu) * rs * g[lane + 64]  + bt[lane + 64]);
    out[dst + lane + 128] = f2b((v2 - mu) * rs * g[lane + 128] + bt[lane + 128]);
}

// ---------- LN2 (token-order) ----------
__global__ __launch_bounds__(256) void ln2_k(
    const float* __restrict__ x, const float* __restrict__ g,
    const float* __restrict__ bt, unsigned short* __restrict__ out)
{
    const int t = (blockIdx.x * 256 + threadIdx.x) >> 6;
    if (t >= MTOK) return;
    const int lane = threadIdx.x & 63;
    const size_t src = (size_t)t * 192;
    const float v0 = x[src + lane], v1 = x[src + lane + 64], v2 = x[src + lane + 128];
    float s1 = v0 + v1 + v2;
    float s2 = v0 * v0 + v1 * v1 + v2 * v2;
    #pragma unroll
    for (int off = 32; off; off >>= 1) {
        s1 += __shfl_xor(s1, off, 64);
        s2 += __shfl_xor(s2, off, 64);
    }
    const float mu = s1 * (1.f / 192.f);
    const float var = s2 * (1.f / 192.f) - mu * mu;
    const float rs = rsqrtf(var + 1e-5f);
    out[src + lane]       = f2b((v0 - mu) * rs * g[lane]       + bt[lane]);
    out[src + lane + 64]  = f2b((v1 - mu) * rs * g[lane + 64]  + bt[lane + 64]);
    out[src + lane + 128] = f2b((v2 - mu) * rs * g[lane + 128] + bt[lane + 128]);
}

// ---------- MFMA GEMM (R15 structure + counted-vmcnt pipeline) ----------
// C[M,N] = A[M,K](bf16) @ W^T[N][K](bf16). tile 128x64, BK=32, dbuf 24 KB.
// K-loop sync: raw s_barrier + s_waitcnt vmcnt(3) — tile t+1's 3 global_load_lds
// stay IN FLIGHT across the barrier (never drain to 0 until the last step).
// Swizzle (verified R10, 0 conflicts): source col ((lane&3)^((lane>>3)&3))*8,
// read col (l4^((l16>>1)&3))*8.
enum { EPI_STORE_BF16 = 0, EPI_PROJ = 1, EPI_GELU = 2, EPI_RES = 3 };

template <int EPI>
__global__ __launch_bounds__(256) void mgemm_k(
    const unsigned short* __restrict__ A, const unsigned short* __restrict__ BT,
    const float* __restrict__ bias, unsigned short* __restrict__ outb,
    float* __restrict__ outf, const float* __restrict__ xres,
    int N, int K, int gx)
{
    __shared__ __align__(16) unsigned short As[2][128 * 32];  // 2x8 KB
    __shared__ __align__(16) unsigned short Bs[2][64 * 32];   // 2x4 KB

    const int nwg = gridDim.x;
    int lin = blockIdx.x;
    lin = (lin & 7) * (nwg >> 3) + (lin >> 3);
    const int bn = lin % gx, bm = lin / gx;
    const int row0 = bm * 128, col0 = bn * 64;

    const int tid = threadIdx.x;
    const int w = tid >> 6, lane = tid & 63;
    const int wr = w >> 1, wc = w & 1;
    const int l16 = lane & 15, l4 = lane >> 4;

    const unsigned short* Ab = A + (size_t)row0 * K;
    const unsigned short* Bb = BT + (size_t)col0 * K;
    const int sr = lane >> 2;
    const int sq = ((lane & 3) ^ ((lane >> 3) & 3)) * 8;

    // prologue: stage tiles 0 and 1 (6 loads/thread in flight)
    #pragma unroll
    for (int i = 0; i < 2; i++) {
        const int ch = w * 2 + i;
        gload_lds16(Ab + (size_t)(ch * 16 + sr) * K + sq, &As[0][ch * 512 + lane * 8]);
    }
    gload_lds16(Bb + (size_t)(w * 16 + sr) * K + sq, &Bs[0][w * 512 + lane * 8]);
    const int nt = K >> 5;
    if (nt > 1) {
        #pragma unroll
        for (int i = 0; i < 2; i++) {
            const int ch = w * 2 + i;
            gload_lds16(Ab + (size_t)(ch * 16 + sr) * K + 32 + sq, &As[1][ch * 512 + lane * 8]);
        }
        gload_lds16(Bb + (size_t)(w * 16 + sr) * K + 32 + sq, &Bs[1][w * 512 + lane * 8]);
    }

    f32x4 acc[4][2];
    #pragma unroll
    for (int m = 0; m < 4; m++)
        #pragma unroll
        for (int n = 0; n < 2; n++) acc[m][n] = (f32x4){0.f, 0.f, 0.f, 0.f};

    const int rdc = (l4 ^ ((l16 >> 1) & 3)) * 8;
    for (int t = 0; t < nt; ++t) {
        const int cur = t & 1;
        // wait for tile t only; tile t+1's 3 loads stay in flight
        if (t + 1 < nt) asm volatile("s_waitcnt vmcnt(3)" ::: "memory");
        else            asm volatile("s_waitcnt vmcnt(0)" ::: "memory");
        __builtin_amdgcn_s_barrier();
        __builtin_amdgcn_sched_barrier(0);   // keep ds_reads below the barrier
        bf16x8 af[4], bf[2];
        #pragma unroll
        for (int m = 0; m < 4; m++)
            af[m] = *reinterpret_cast<const bf16x8*>(
                &As[cur][(wr * 64 + m * 16 + l16) * 32 + rdc]);
        #pragma unroll
        for (int n = 0; n < 2; n++)
            bf[n] = *reinterpret_cast<const bf16x8*>(
                &Bs[cur][(wc * 32 + n * 16 + l16) * 32 + rdc]);
        #pragma unroll
        for (int m = 0; m < 4; m++)
            #pragma unroll
            for (int n = 0; n < 2; n++)
                acc[m][n] = __builtin_amdgcn_mfma_f32_16x16x32_bf16(
                    af[m], bf[n], acc[m][n], 0, 0, 0);
        __builtin_amdgcn_sched_barrier(0);   // all reads of buf[cur] issued above
        __builtin_amdgcn_s_barrier();        // all waves done reading buf[cur]
        if (t + 2 < nt) {
            const int k0 = (t + 2) << 5;
            #pragma unroll
            for (int i = 0; i < 2; i++) {
                const int ch = w * 2 + i;
                gload_lds16(Ab + (size_t)(ch * 16 + sr) * K + k0 + sq,
                            &As[cur][ch * 512 + lane * 8]);
            }
            gload_lds16(Bb + (size_t)(w * 16 + sr) * K + k0 + sq,
                        &Bs[cur][w * 512 + lane * 8]);
        }
    }

    float bv[2];
    #pragma unroll
    for (int n = 0; n < 2; n++) bv[n] = bias[col0 + wc * 32 + n * 16 + l16];

    #pragma unroll
    for (int m = 0; m < 4; m++) {
        #pragma unroll
        for (int j = 0; j < 4; j++) {
            const int row = row0 + wr * 64 + m * 16 + l4 * 4 + j;
            if constexpr (EPI == EPI_PROJ) {
                const int widx = row / 49, n49 = row - widx * 49;
                const int b = widx >> 6, win = widx & 63;
                const int wh = win >> 3, ww = win & 7;
                const int r = n49 / 7, cc = n49 - r * 7;
                int hh = wh * 7 + r + 3;  if (hh >= 56) hh -= 56;
                int wcc = ww * 7 + cc + 3; if (wcc >= 56) wcc -= 56;
                const size_t tok = ((size_t)b * 3136 + hh * 56 + wcc) * 192;
                #pragma unroll
                for (int n = 0; n < 2; n++) {
                    const int col = col0 + wc * 32 + n * 16 + l16;
                    outf[tok + col] = xres[tok + col] + acc[m][n][j] + bv[n];
                }
            } else if constexpr (EPI == EPI_STORE_BF16) {
                #pragma unroll
                for (int n = 0; n < 2; n++) {
                    const int col = col0 + wc * 32 + n * 16 + l16;
                    outb[(size_t)row * N + col] = f2b(acc[m][n][j] + bv[n]);
                }
            } else if constexpr (EPI == EPI_GELU) {
                #pragma unroll
                for (int n = 0; n < 2; n++) {
                    const int col = col0 + wc * 32 + n * 16 + l16;
                    float v = acc[m][n][j] + bv[n];
                    const float wv = v + 0.044715f * v * v * v;
                    const float sg = __builtin_amdgcn_rcpf(
                        1.f + __expf(-1.5957691216057308f * wv));
                    v = v * sg;
                    outb[(size_t)row * N + col] = f2b(v);
                }
            } else {  // EPI_RES
                #pragma unroll
                for (int n = 0; n < 2; n++) {
                    const int col = col0 + wc * 32 + n * 16 + l16;
                    outf[(size_t)row * N + col] += acc[m][n][j] + bv[n];
                }
            }
        }
    }
}

// ---------- MFMA attention: one wave (64 thr) per (window, head) ----------
__global__ __launch_bounds__(64) void attn_mfma_k(
    const unsigned short* __restrict__ qkv, const float* __restrict__ rpb,
    unsigned short* __restrict__ out)
{
    const int blk = blockIdx.x;
    const int widx = blk / 6, head = blk - widx * 6;
    const int win = widx & 63;
    const int wh = win >> 3, ww = win & 7;

    __shared__ __align__(16) unsigned short vt[32 * 72];  // V^T [d][m], stride 72
    __shared__ __align__(16) unsigned short pl[64 * 72];  // P  [n][m], stride 72
    __shared__ float bias_s[256];

    const int lane = threadIdx.x;
    const int l16 = lane & 15, l4 = lane >> 4;
    const size_t base = (size_t)widx * 49 * 576 + (size_t)head * 32;

    for (int i = lane; i < 169; i += 64) bias_s[i] = rpb[i * 6 + head];

    #pragma unroll
    for (int it = 0; it < 4; ++it) {
        const int c = lane + it * 64;
        const int m = c >> 2, d8 = (c & 3) * 8;
        bf16x8 v8 = {};
        if (m < 49)
            v8 = *reinterpret_cast<const bf16x8*>(qkv + base + (size_t)m * 576 + 384 + d8);
        #pragma unroll
        for (int r = 0; r < 8; ++r) vt[(d8 + r) * 72 + m] = (unsigned short)v8[r];
    }

    bf16x8 kf[4], qf[4];
    #pragma unroll
    for (int f = 0; f < 4; ++f) {
        const int rrow = f * 16 + l16;
        bf16x8 kz = {}, qz = {};
        if (rrow < 49) {
            kz = *reinterpret_cast<const bf16x8*>(qkv + base + (size_t)rrow * 576 + 192 + l4 * 8);
            qz = *reinterpret_cast<const bf16x8*>(qkv + base + (size_t)rrow * 576 + l4 * 8);
        }
        kf[f] = kz; qf[f] = qz;
    }

    f32x4 acc[4][4];
    #pragma unroll
    for (int mf = 0; mf < 4; ++mf)
        #pragma unroll
        for (int nf = 0; nf < 4; ++nf) {
            f32x4 z = (f32x4){0.f, 0.f, 0.f, 0.f};
            acc[mf][nf] = __builtin_amdgcn_mfma_f32_16x16x32_bf16(kf[mf], qf[nf], z, 0, 0, 0);
        }

    __syncthreads();

    int gn[4], labn[4]; bool nok[4];
    #pragma unroll
    for (int nf = 0; nf < 4; ++nf) {
        const int n = nf * 16 + l16;
        const int rn = (n * 9363) >> 16, cn = n - rn * 7;
        gn[nf] = n + 6 * rn;
        labn[nf] = (wh == 7 ? (rn < 4 ? 1 : 2) : 0) * 3 + (ww == 7 ? (cn < 4 ? 1 : 2) : 0);
        nok[nf] = (n < 49);
    }

    #pragma unroll
    for (int mf = 0; mf < 4; ++mf) {
        #pragma unroll
        for (int j = 0; j < 4; ++j) {
            const int m = mf * 16 + l4 * 4 + j;
            const int rm = (m * 9363) >> 16, cm = m - rm * 7;
            const int gm = m + 6 * rm;
            const int labm = (wh == 7 ? (rm < 4 ? 1 : 2) : 0) * 3 + (ww == 7 ? (cm < 4 ? 1 : 2) : 0);
            const bool mok = (m < 49);
            #pragma unroll
            for (int nf = 0; nf < 4; ++nf) {
                float s = -1e30f;
                if (mok && nok[nf]) {
                    s = acc[mf][nf][j] * SCALE_ + bias_s[gn[nf] - gm + 84];
                    if (labn[nf] != labm) s -= 100.f;
                }
                acc[mf][nf][j] = s;
            }
        }
    }

    #pragma unroll
    for (int nf = 0; nf < 4; ++nf) {
        float mx = -1e30f;
        #pragma unroll
        for (int mf = 0; mf < 4; ++mf)
            #pragma unroll
            for (int j = 0; j < 4; ++j) mx = fmaxf(mx, acc[mf][nf][j]);
        mx = fmaxf(mx, __shfl_xor(mx, 16, 64));
        mx = fmaxf(mx, __shfl_xor(mx, 32, 64));
        float sum = 0.f;
        #pragma unroll
        for (int mf = 0; mf < 4; ++mf)
            #pragma unroll
            for (int j = 0; j < 4; ++j) {
                const float e = __expf(acc[mf][nf][j] - mx);
                acc[mf][nf][j] = e;
                sum += e;
            }
        sum += __shfl_xor(sum, 16, 64);
        sum += __shfl_xor(sum, 32, 64);
        const float inv = 1.f / sum;
        const int n = nf * 16 + l16;
        #pragma unroll
        for (int mf = 0; mf < 4; ++mf)
            #pragma unroll
            for (int jp = 0; jp < 2; ++jp) {
                const int m = mf * 16 + l4 * 4 + jp * 2;
                const unsigned int pk =
                    (unsigned int)f2b(acc[mf][nf][jp * 2] * inv) |
                    ((unsigned int)f2b(acc[mf][nf][jp * 2 + 1] * inv) << 16);
                *reinterpret_cast<unsigned int*>(&pl[n * 72 + m]) = pk;
            }
    }
    __syncthreads();

    f32x4 oacc[4][2];
    #pragma unroll
    for (int nf = 0; nf < 4; ++nf)
        #pragma unroll
        for (int df = 0; df < 2; ++df) oacc[nf][df] = (f32x4){0.f, 0.f, 0.f, 0.f};
    #pragma unroll
    for (int ks = 0; ks < 2; ++ks) {
        bf16x8 vf[2];
        #pragma unroll
        for (int df = 0; df < 2; ++df)
            vf[df] = *reinterpret_cast<const bf16x8*>(&vt[(df * 16 + l16) * 72 + ks * 32 + l4 * 8]);
        #pragma unroll
        for (int nf = 0; nf < 4; ++nf) {
            const bf16x8 pf = *reinterpret_cast<const bf16x8*>(&pl[(nf * 16 + l16) * 72 + ks * 32 + l4 * 8]);
            #pragma unroll
            for (int df = 0; df < 2; ++df)
                oacc[nf][df] = __builtin_amdgcn_mfma_f32_16x16x32_bf16(pf, vf[df], oacc[nf][df], 0, 0, 0);
        }
    }

    #pragma unroll
    for (int nf = 0; nf < 4; ++nf)
        #pragma unroll
        for (int j = 0; j < 4; ++j) {
            const int n = nf * 16 + l4 * 4 + j;
            if (n < 49) {
                const size_t o = ((size_t)widx * 49 + n) * 192 + (size_t)head * 32;
                out[o + l16]      = f2b(oacc[nf][0][j]);
                out[o + 16 + l16] = f2b(oacc[nf][1][j]);
            }
        }
}

// ---------- launch ----------
extern "C" void kernel_launch(void* const* d_in, const int* in_sizes, int n_in,
                              void* d_out, int out_size, void* d_ws, size_t ws_size,
                              hipStream_t stream)
{
    const float* x      = (const float*)d_in[0];
    const float* n1g    = (const float*)d_in[1];
    const float* n1b    = (const float*)d_in[2];
    const float* qkv_w  = (const float*)d_in[3];
    const float* qkv_b  = (const float*)d_in[4];
    const float* rpb    = (const float*)d_in[5];
    const float* proj_w = (const float*)d_in[6];
    const float* proj_b = (const float*)d_in[7];
    const float* n2g    = (const float*)d_in[8];
    const float* n2b    = (const float*)d_in[9];
    const float* fc1_w  = (const float*)d_in[10];
    const float* fc1_b  = (const float*)d_in[11];
    const float* fc2_w  = (const float*)d_in[12];
    const float* fc2_b  = (const float*)d_in[13];
    float* out = (float*)d_out;

    const int M = MTOK;  // 100352 = 784*128
    unsigned short* big   = (unsigned short*)d_ws;          // M*768
    unsigned short* winx  = big + (size_t)M * 768;          // M*192 (ln1-win, attn-out, ln2-out)
    unsigned short* qkvT  = winx + (size_t)M * 192;         // 576*192
    unsigned short* projT = qkvT + 576 * 192;               // 192*192
    unsigned short* fc1T  = projT + 192 * 192;              // 768*192
    unsigned short* fc2T  = fc1T + 768 * 192;               // 192*768

    // 0) weights -> bf16 transposed
    wconv_k<<<(576 * 192 + 255) / 256, 256, 0, stream>>>(qkv_w, qkvT, 192, 576);
    wconv_k<<<(192 * 192 + 255) / 256, 256, 0, stream>>>(proj_w, projT, 192, 192);
    wconv_k<<<(768 * 192 + 255) / 256, 256, 0, stream>>>(fc1_w, fc1T, 192, 768);
    wconv_k<<<(192 * 768 + 255) / 256, 256, 0, stream>>>(fc2_w, fc2T, 768, 192);

    // 1) LN1 + shift + window partition -> winx (bf16)
    ln1_window_k<<<M / 4, 256, 0, stream>>>(x, n1g, n1b, winx);
    // 2) qkv: (M,192)@(192,576) -> big
    mgemm_k<EPI_STORE_BF16><<<9 * (M / 128), 256, 0, stream>>>(
        winx, qkvT, qkv_b, big, nullptr, nullptr, 576, 192, 9);
    // 3) attention (MFMA, one wave per window×head) -> winx
    attn_mfma_k<<<2048 * 6, 64, 0, stream>>>(big, rpb, winx);
    // 4) proj + window-reverse + unshift + residual -> d_out (f32)
    mgemm_k<EPI_PROJ><<<3 * (M / 128), 256, 0, stream>>>(
        winx, projT, proj_b, nullptr, out, x, 192, 192, 3);
    // 5) LN2 -> winx (bf16)
    ln2_k<<<M / 4, 256, 0, stream>>>(out, n2g, n2b, winx);
    // 6) fc1 + GELU -> big
    mgemm_k<EPI_GELU><<<12 * (M / 128), 256, 0, stream>>>(
        winx, fc1T, fc1_b, big, nullptr, nullptr, 768, 192, 12);
    // 7) fc2 + residual -> d_out
    mgemm_k<EPI_RES><<<3 * (M / 128), 256, 0, stream>>>(
        big, fc2T, fc2_b, nullptr, out, nullptr, 192, 768, 3);
}